// Round 7
// baseline (517.358 us; speedup 1.0000x reference)
//
#include <hip/hip_runtime.h>
#include <hip/hip_bf16.h>

#define HDD 64
#define NH 16
#define SEQ 2048
#define DM 1024
#define BB 4

using bf16x8 = __attribute__((ext_vector_type(8))) short;
using bf16x4 = __attribute__((ext_vector_type(4))) short;
using floatx4 = __attribute__((ext_vector_type(4))) float;
typedef unsigned int u32;

__device__ __forceinline__ short f2bf(float f) {
    __hip_bfloat16 h = __float2bfloat16(f);
    union { __hip_bfloat16 h; short s; } c;
    c.h = h;
    return c.s;
}

// HW packed fp32->bf16 (RNE), 2 floats -> 1 dword: lo -> [15:0], hi -> [31:16]
__device__ __forceinline__ u32 cvt_pk_bf16(float lo, float hi) {
    u32 r;
    asm("v_cvt_pk_bf16_f32 %0, %1, %2" : "=v"(r) : "v"(lo), "v"(hi));
    return r;
}

// Convert 8 contiguous fp32 -> 8 bf16 (HW cvt_pk).
__device__ __forceinline__ void stage8f(short* dst, const float* s) {
    float4 a = *(const float4*)s;
    float4 b = *(const float4*)(s + 4);
    union { u32 u[4]; bf16x8 v; } r;
    r.u[0] = cvt_pk_bf16(a.x, a.y);
    r.u[1] = cvt_pk_bf16(a.z, a.w);
    r.u[2] = cvt_pk_bf16(b.x, b.y);
    r.u[3] = cvt_pk_bf16(b.z, b.w);
    *(bf16x8*)dst = r.v;
}

__device__ __forceinline__ float vmax4(floatx4 v) {
    return fmaxf(fmaxf(v[0], v[1]), fmaxf(v[2], v[3]));
}

// ---------------------------------------------------------------------------
// Bulk fp32->bf16 convert: 4 weight matrices (1M elems) + 3 inputs (8.39M).
// ---------------------------------------------------------------------------
__global__ __launch_bounds__(256) void conv_kernel(
    const float* __restrict__ w0, const float* __restrict__ w1,
    const float* __restrict__ w2, const float* __restrict__ w3,
    const float* __restrict__ x0, const float* __restrict__ x1,
    const float* __restrict__ x2,
    short* __restrict__ ow0, short* __restrict__ ow1,
    short* __restrict__ ow2, short* __restrict__ ow3,
    short* __restrict__ ox0, short* __restrict__ ox1,
    short* __restrict__ ox2)
{
    const int z = blockIdx.y;
    const float* src;
    short* dst;
    switch (z) {
        case 0: src = w0; dst = ow0; break;
        case 1: src = w1; dst = ow1; break;
        case 2: src = w2; dst = ow2; break;
        case 3: src = w3; dst = ow3; break;
        case 4: src = x0; dst = ox0; break;
        case 5: src = x1; dst = ox1; break;
        default: src = x2; dst = ox2; break;
    }
    if (z < 4 && blockIdx.x >= 512) return;   // weights: 1M elems only
    size_t i = ((size_t)blockIdx.x * 256 + threadIdx.x) * 8;
    stage8f(dst + i, src + i);
}

// ---------------------------------------------------------------------------
// QKV projection: Y = X @ W^T + b (both operands bf16), written head-split
// as [B,H,S,HD] bf16. For Q (z==0), 0.125*log2(e) is folded in so the
// attention kernel can use exp2 on unscaled MFMA scores.
// ---------------------------------------------------------------------------
__global__ __launch_bounds__(256) void proj_kernel(
    const short* __restrict__ xq, const short* __restrict__ xk, const short* __restrict__ xv,
    const short* __restrict__ wqb, const float* __restrict__ bq,
    const short* __restrict__ wkb, const float* __restrict__ bk,
    const short* __restrict__ wvb, const float* __restrict__ bv,
    short* __restrict__ Qh, short* __restrict__ Kh, short* __restrict__ Vh)
{
    const int z = blockIdx.z;
    const short* X  = (z == 0) ? xq  : (z == 1) ? xk  : xv;
    const short* Wb = (z == 0) ? wqb : (z == 1) ? wkb : wvb;
    const float* Bp = (z == 0) ? bq  : (z == 1) ? bk  : bv;
    short* Dst      = (z == 0) ? Qh  : (z == 1) ? Kh  : Vh;
    const float qscale = (z == 0) ? (0.125f * 1.44269504088896f) : 1.0f;

    const int m0 = blockIdx.x * 128;
    const int n0 = blockIdx.y * 128;
    const int tid = threadIdx.x;
    const int w = tid >> 6, lane = tid & 63, lc = lane & 15, lq = lane >> 4;
    const int wm = w >> 1, wn = w & 1;

    __shared__ alignas(16) short As[128 * 40];
    __shared__ alignas(16) short Bs[128 * 40];

    floatx4 acc[4][4];
#pragma unroll
    for (int i = 0; i < 4; i++)
#pragma unroll
        for (int j = 0; j < 4; j++) acc[i][j] = floatx4{0.f, 0.f, 0.f, 0.f};

    for (int kt = 0; kt < DM / 32; ++kt) {
        __syncthreads();
#pragma unroll
        for (int c = 0; c < 2; ++c) {
            int chunk = c * 256 + tid;
            int row = chunk >> 2;
            int col = (chunk & 3) * 8;
            *(bf16x8*)(As + row * 40 + col) =
                *(const bf16x8*)(X + (size_t)(m0 + row) * DM + kt * 32 + col);
            *(bf16x8*)(Bs + row * 40 + col) =
                *(const bf16x8*)(Wb + (size_t)(n0 + row) * DM + kt * 32 + col);
        }
        __syncthreads();

        bf16x8 aF[4], bF[4];
#pragma unroll
        for (int i = 0; i < 4; i++)
            aF[i] = *(const bf16x8*)(As + (wm * 64 + i * 16 + lc) * 40 + lq * 8);
#pragma unroll
        for (int j = 0; j < 4; j++)
            bF[j] = *(const bf16x8*)(Bs + (wn * 64 + j * 16 + lc) * 40 + lq * 8);
        __builtin_amdgcn_s_setprio(1);
#pragma unroll
        for (int i = 0; i < 4; i++)
#pragma unroll
            for (int j = 0; j < 4; j++)
                acc[i][j] = __builtin_amdgcn_mfma_f32_16x16x32_bf16(aF[i], bF[j], acc[i][j], 0, 0, 0);
        __builtin_amdgcn_s_setprio(0);
    }

#pragma unroll
    for (int j = 0; j < 4; j++) {
        int n = n0 + wn * 64 + j * 16 + lc;
        float bias = Bp[n];
        int h = n >> 6, hd = n & 63;
#pragma unroll
        for (int i = 0; i < 4; i++) {
#pragma unroll
            for (int r = 0; r < 4; r++) {
                int m = m0 + wm * 64 + i * 16 + lq * 4 + r;
                int b = m >> 11, s = m & 2047;
                float val = (acc[i][j][r] + bias) * qscale;
                Dst[(((size_t)(b * NH + h)) * SEQ + s) * HDD + hd] = f2bf(val);
            }
        }
    }
}

// ---------------------------------------------------------------------------
// Flash attention, swapped-operand QK^T, 8 waves/block (128 q-rows),
// two kv-tiles (128 kv) per iteration:
//   S^T = mfma(A=K, B=Q)  ->  lane (lc,lq) holds S^T[kv=nt*16+lq*4+r][q=lc]
// Softmax: in-lane trees + 2 shfl_xor per 128 kv; defer-max (THR=8, log2).
// P packed with HW cvt_pk into a WAVE-LOCAL LDS row (no barrier, no
// bpermute), ONE 64-kv tile at a time: write offsets nt*16+lq*4 in [0,60],
// read offsets f*32+lq*8 in [0,56] -- both < row stride 72. The t=1 write
// reuses the row after t=0's reads (same-wave DS ops are program-ordered).
// V^T in XOR-swizzled, double-buffered LDS, one barrier per 128 kv.
// Static LDS total = 36864 + 18432 = 55296 B (< 64 KB limit).
// ---------------------------------------------------------------------------
__global__ __launch_bounds__(512) void attn_kernel(
    const short* __restrict__ Qh, const short* __restrict__ Kh,
    const short* __restrict__ Vh, float* __restrict__ ctxout,
    short* __restrict__ ctxb)
{
    // XCD swizzle: 1024 blocks / 8 XCDs -> each XCD owns 8 (b,h) pairs.
    const int linear = blockIdx.y * 16 + blockIdx.x;
    const int swz = (linear & 7) * 128 + (linear >> 3);
    const int qb = swz & 15;
    const int bh = swz >> 4;

    const int tid = threadIdx.x;
    const int w = tid >> 6, lane = tid & 63, lc = lane & 15, lq = lane >> 4;
    const int qbase = qb * 128 + w * 16;

    const short* Qp = Qh + (size_t)bh * SEQ * HDD;
    const short* Kp = Kh + (size_t)bh * SEQ * HDD;
    const short* Vp = Vh + (size_t)bh * SEQ * HDD;

    // V transposed: Vt[buf][half][d*72 + (kv ^ ((d>>3)&7)*8)]  (36,864 B)
    __shared__ alignas(16) short Vt[2][2][64 * 72];
    // Per-wave P scratch: [q=16][one 64-kv tile + 8 pad]  (18,432 B)
    __shared__ alignas(16) short Pl[8][16][72];

    bf16x8 aQ[2];
#pragma unroll
    for (int f = 0; f < 2; ++f)
        aQ[f] = *(const bf16x8*)(Qp + (size_t)(qbase + lc) * HDD + f * 32 + lq * 8);

    float mOld = -1e30f, lSum = 0.f;
    floatx4 accO[4];
#pragma unroll
    for (int dt = 0; dt < 4; dt++) accO[dt] = floatx4{0.f, 0.f, 0.f, 0.f};

    // staging map: 256 threads per half-tile; thread stages 2 kv rows x 8 d
    const int half = tid >> 8;
    const int t8 = tid & 255;
    const int kv2 = (t8 >> 3) * 2;
    const int d0 = (t8 & 7) * 8;
    const int swzb = (t8 & 7) << 3;
    const int kvs_w = kv2 ^ swzb;

    // prologue: stage pair 0 into buf 0
    {
        const short* vp = Vp + (size_t)(half * 64 + kv2) * HDD + d0;
        bf16x8 v0 = *(const bf16x8*)vp;
        bf16x8 v1 = *(const bf16x8*)(vp + HDD);
        short* dstb = &Vt[0][half][0];
#pragma unroll
        for (int i = 0; i < 8; i++) {
            u32 pk = ((u32)(unsigned short)v0[i]) | (((u32)(unsigned short)v1[i]) << 16);
            *(u32*)(dstb + (d0 + i) * 72 + kvs_w) = pk;
        }
    }
    __syncthreads();

    short* plw = &Pl[w][0][0] + lc * 72;   // this lane's P row (q = lc)

    const int NP = SEQ / 128;  // 16 iterations
    for (int kp = 0; kp < NP; ++kp) {
        const int cur = kp & 1;
        const int kv0 = kp * 128;
        const bool have = (kp + 1 < NP);

        // early-issue next pair's V loads (hide under QK+softmax+PV)
        bf16x8 nv0{}, nv1{};
        if (have) {
            const short* nvp = Vp + (size_t)(kv0 + 128 + half * 64 + kv2) * HDD + d0;
            nv0 = *(const bf16x8*)nvp;
            nv1 = *(const bf16x8*)(nvp + HDD);
        }

        // QK^T for both tiles (scores in log2-units; scale folded into Q)
        floatx4 sc0[4], sc1[4];
        __builtin_amdgcn_s_setprio(1);
#pragma unroll
        for (int nt = 0; nt < 4; nt++) {
            floatx4 sv = floatx4{0.f, 0.f, 0.f, 0.f};
#pragma unroll
            for (int f = 0; f < 2; f++) {
                bf16x8 bK = *(const bf16x8*)(Kp + (size_t)(kv0 + nt * 16 + lc) * HDD + f * 32 + lq * 8);
                sv = __builtin_amdgcn_mfma_f32_16x16x32_bf16(bK, aQ[f], sv, 0, 0, 0);
            }
            sc0[nt] = sv;
        }
#pragma unroll
        for (int nt = 0; nt < 4; nt++) {
            floatx4 sv = floatx4{0.f, 0.f, 0.f, 0.f};
#pragma unroll
            for (int f = 0; f < 2; f++) {
                bf16x8 bK = *(const bf16x8*)(Kp + (size_t)(kv0 + 64 + nt * 16 + lc) * HDD + f * 32 + lq * 8);
                sv = __builtin_amdgcn_mfma_f32_16x16x32_bf16(bK, aQ[f], sv, 0, 0, 0);
            }
            sc1[nt] = sv;
        }
        __builtin_amdgcn_s_setprio(0);

        // max over 128 kv: in-lane tree + 2 shfl
        float ma = fmaxf(fmaxf(vmax4(sc0[0]), vmax4(sc0[1])),
                         fmaxf(vmax4(sc0[2]), vmax4(sc0[3])));
        float mb = fmaxf(fmaxf(vmax4(sc1[0]), vmax4(sc1[1])),
                         fmaxf(vmax4(sc1[2]), vmax4(sc1[3])));
        float mx = fmaxf(ma, mb);
        mx = fmaxf(mx, __shfl_xor(mx, 16, 64));
        mx = fmaxf(mx, __shfl_xor(mx, 32, 64));
        if (!__all(mx - mOld <= 8.0f)) {
            const float mNew = fmaxf(mOld, mx);
            const float alpha = __builtin_amdgcn_exp2f(mOld - mNew);
            lSum *= alpha;
#pragma unroll
            for (int dt = 0; dt < 4; dt++)
#pragma unroll
                for (int r = 0; r < 4; r++) accO[dt][r] *= alpha;
            mOld = mNew;
        }

        // exp2 + tree-sum
        float part[8];
#pragma unroll
        for (int nt = 0; nt < 4; nt++) {
            floatx4 p0 = sc0[nt], p1 = sc1[nt];
#pragma unroll
            for (int r = 0; r < 4; r++) {
                p0[r] = __builtin_amdgcn_exp2f(p0[r] - mOld);
                p1[r] = __builtin_amdgcn_exp2f(p1[r] - mOld);
            }
            sc0[nt] = p0; sc1[nt] = p1;
            part[nt]     = (p0[0] + p0[1]) + (p0[2] + p0[3]);
            part[4 + nt] = (p1[0] + p1[1]) + (p1[2] + p1[3]);
        }
        float rsum = ((part[0] + part[1]) + (part[2] + part[3])) +
                     ((part[4] + part[5]) + (part[6] + part[7]));
        rsum += __shfl_xor(rsum, 16, 64);
        rsum += __shfl_xor(rsum, 32, 64);
        lSum += rsum;

        // PV per 64-kv tile: write P_t to the wave-local row (offsets
        // nt*16+lq*4 <= 60 < 72), read back as B-fragments, 8 MFMA.
        // t=1 overwrites t=0's row AFTER t=0's reads: same-wave DS ops are
        // in-order; RAW handled by compiler lgkmcnt.
#pragma unroll
        for (int t = 0; t < 2; t++) {
            floatx4* sc = (t == 0) ? sc0 : sc1;
#pragma unroll
            for (int nt = 0; nt < 4; nt++) {
                uint2 pr;
                pr.x = cvt_pk_bf16(sc[nt][0], sc[nt][1]);
                pr.y = cvt_pk_bf16(sc[nt][2], sc[nt][3]);
                *(uint2*)(plw + nt * 16 + lq * 4) = pr;
            }
            const short* vtb = &Vt[cur][t][0];
#pragma unroll
            for (int f = 0; f < 2; f++) {
                bf16x8 aP = *(const bf16x8*)(plw + f * 32 + lq * 8);
                __builtin_amdgcn_s_setprio(1);
#pragma unroll
                for (int dt = 0; dt < 4; dt++) {
                    const int d = dt * 16 + lc;
                    const int kvs = (f * 32 + lq * 8) ^ (((d >> 3) & 7) << 3);
                    bf16x8 bV = *(const bf16x8*)(vtb + d * 72 + kvs);
                    accO[dt] = __builtin_amdgcn_mfma_f32_16x16x32_bf16(bV, aP, accO[dt], 0, 0, 0);
                }
                __builtin_amdgcn_s_setprio(0);
            }
        }

        // write next pair's V into the other buffer
        if (have) {
            short* dstb = &Vt[cur ^ 1][half][0];
#pragma unroll
            for (int i = 0; i < 8; i++) {
                u32 pk = ((u32)(unsigned short)nv0[i]) | (((u32)(unsigned short)nv1[i]) << 16);
                *(u32*)(dstb + (d0 + i) * 72 + kvs_w) = pk;
            }
        }
        __syncthreads();
    }

    // epilogue: ctx[b,h,q,d] = O^T[d][q] / l (fp32 to d_out, bf16 to ws)
    const float inv = 1.0f / lSum;
    const size_t rowoff = ((size_t)bh * SEQ + qbase + lc) * HDD;
    float* orow = ctxout + rowoff;
    short* brow = ctxb + rowoff;
#pragma unroll
    for (int dt = 0; dt < 4; dt++) {
        float4 st;
        st.x = accO[dt][0] * inv;
        st.y = accO[dt][1] * inv;
        st.z = accO[dt][2] * inv;
        st.w = accO[dt][3] * inv;
        *(float4*)(orow + dt * 16 + lq * 4) = st;
        uint2 bb;
        bb.x = cvt_pk_bf16(st.x, st.y);
        bb.y = cvt_pk_bf16(st.z, st.w);
        *(uint2*)(brow + dt * 16 + lq * 4) = bb;
    }
}

// ---------------------------------------------------------------------------
// Output projection: out = merged(ctx) @ Wo^T + bo. Both operands bf16.
// ---------------------------------------------------------------------------
__global__ __launch_bounds__(256) void outproj_kernel(
    const short* __restrict__ ctxb, const short* __restrict__ wob,
    const float* __restrict__ bo, float* __restrict__ out)
{
    const int m0 = blockIdx.x * 128;
    const int n0 = blockIdx.y * 128;
    const int tid = threadIdx.x;
    const int w = tid >> 6, lane = tid & 63, lc = lane & 15, lq = lane >> 4;
    const int wm = w >> 1, wn = w & 1;

    __shared__ alignas(16) short As[128 * 40];
    __shared__ alignas(16) short Bs[128 * 40];

    floatx4 acc[4][4];
#pragma unroll
    for (int i = 0; i < 4; i++)
#pragma unroll
        for (int j = 0; j < 4; j++) acc[i][j] = floatx4{0.f, 0.f, 0.f, 0.f};

    for (int kt = 0; kt < DM / 32; ++kt) {
        __syncthreads();
#pragma unroll
        for (int c = 0; c < 2; ++c) {
            int chunk = c * 256 + tid;
            int row = chunk >> 2;
            int col = (chunk & 3) * 8;
            int m = m0 + row;
            int b = m >> 11, s = m & 2047;
            int kcol = kt * 32 + col;
            int h = kcol >> 6, hd = kcol & 63;
            *(bf16x8*)(As + row * 40 + col) =
                *(const bf16x8*)(ctxb + (((size_t)(b * NH + h)) * SEQ + s) * HDD + hd);
            *(bf16x8*)(Bs + row * 40 + col) =
                *(const bf16x8*)(wob + (size_t)(n0 + row) * DM + kt * 32 + col);
        }
        __syncthreads();

        bf16x8 aF[4], bF[4];
#pragma unroll
        for (int i = 0; i < 4; i++)
            aF[i] = *(const bf16x8*)(As + (wm * 64 + i * 16 + lc) * 40 + lq * 8);
#pragma unroll
        for (int j = 0; j < 4; j++)
            bF[j] = *(const bf16x8*)(Bs + (wn * 64 + j * 16 + lc) * 40 + lq * 8);
        __builtin_amdgcn_s_setprio(1);
#pragma unroll
        for (int i = 0; i < 4; i++)
#pragma unroll
            for (int j = 0; j < 4; j++)
                acc[i][j] = __builtin_amdgcn_mfma_f32_16x16x32_bf16(aF[i], bF[j], acc[i][j], 0, 0, 0);
        __builtin_amdgcn_s_setprio(0);
    }

#pragma unroll
    for (int j = 0; j < 4; j++) {
        int n = n0 + wn * 64 + j * 16 + lc;
        float bias = bo[n];
#pragma unroll
        for (int i = 0; i < 4; i++) {
#pragma unroll
            for (int r = 0; r < 4; r++) {
                int m = m0 + wm * 64 + i * 16 + lq * 4 + r;
                out[(size_t)m * DM + n] = acc[i][j][r] + bias;
            }
        }
    }
}

extern "C" void kernel_launch(void* const* d_in, const int* in_sizes, int n_in,
                              void* d_out, int out_size, void* d_ws, size_t ws_size,
                              hipStream_t stream) {
    const float* q  = (const float*)d_in[0];
    const float* k  = (const float*)d_in[1];
    const float* v  = (const float*)d_in[2];
    const float* wq = (const float*)d_in[3];
    const float* bq = (const float*)d_in[4];
    const float* wk = (const float*)d_in[5];
    const float* bk = (const float*)d_in[6];
    const float* wv = (const float*)d_in[7];
    const float* bv = (const float*)d_in[8];
    const float* wo = (const float*)d_in[9];
    const float* bo = (const float*)d_in[10];

    float* out0 = (float*)d_out;                          // [B,S,D] fp32
    float* ctx  = out0 + (size_t)BB * SEQ * DM;           // [B,H,S,HD] fp32

    const size_t NELEM = (size_t)BB * NH * SEQ * HDD;     // 8.39M
    short* Qh   = (short*)d_ws;
    short* Kh   = Qh + NELEM;
    short* Vh   = Kh + NELEM;
    short* ctxb = Vh + NELEM;           // written by attn; until then holds Xv
    short* Wqb  = ctxb + NELEM;
    short* Wkb  = Wqb + (size_t)DM * DM;
    short* Wvb  = Wkb + (size_t)DM * DM;
    short* Wob  = Wvb + (size_t)DM * DM;
    // bf16 X: Xq/Xk borrow d_out's out0 region (written only by outproj at
    // the end); Xv aliases ctxb (written only by attn, after proj reads Xv).
    short* Xq = (short*)out0;
    short* Xk = Xq + NELEM;
    short* Xv = ctxb;

    conv_kernel<<<dim3(4096, 7), 256, 0, stream>>>(
        wq, wk, wv, wo, q, k, v, Wqb, Wkb, Wvb, Wob, Xq, Xk, Xv);
    proj_kernel<<<dim3(64, 8, 3), 256, 0, stream>>>(
        Xq, Xk, Xv, Wqb, bq, Wkb, bk, Wvb, bv, Qh, Kh, Vh);
    attn_kernel<<<dim3(16, 64), 512, 0, stream>>>(Qh, Kh, Vh, ctx, ctxb);
    outproj_kernel<<<dim3(64, 8), 256, 0, stream>>>(ctxb, Wob, bo, out0);
}

// Round 8
// 496.272 us; speedup vs baseline: 1.0425x; 1.0425x over previous
//
#include <hip/hip_runtime.h>
#include <hip/hip_bf16.h>

#define HDD 64
#define NH 16
#define SEQ 2048
#define DM 1024
#define BB 4

using bf16x8 = __attribute__((ext_vector_type(8))) short;
using bf16x4 = __attribute__((ext_vector_type(4))) short;
using floatx4 = __attribute__((ext_vector_type(4))) float;
typedef unsigned int u32;

__device__ __forceinline__ short f2bf(float f) {
    __hip_bfloat16 h = __float2bfloat16(f);
    union { __hip_bfloat16 h; short s; } c;
    c.h = h;
    return c.s;
}

// HW packed fp32->bf16 (RNE), 2 floats -> 1 dword: lo -> [15:0], hi -> [31:16]
__device__ __forceinline__ u32 cvt_pk_bf16(float lo, float hi) {
    u32 r;
    asm("v_cvt_pk_bf16_f32 %0, %1, %2" : "=v"(r) : "v"(lo), "v"(hi));
    return r;
}

// Convert 8 contiguous fp32 -> 8 bf16 (HW cvt_pk).
__device__ __forceinline__ void stage8f(short* dst, const float* s) {
    float4 a = *(const float4*)s;
    float4 b = *(const float4*)(s + 4);
    union { u32 u[4]; bf16x8 v; } r;
    r.u[0] = cvt_pk_bf16(a.x, a.y);
    r.u[1] = cvt_pk_bf16(a.z, a.w);
    r.u[2] = cvt_pk_bf16(b.x, b.y);
    r.u[3] = cvt_pk_bf16(b.z, b.w);
    *(bf16x8*)dst = r.v;
}

// Async global->LDS, 16 bytes per lane. LDS dest is wave-uniform base +
// lane*16 (linear); global src is per-lane.
__device__ __forceinline__ void gload16(const short* g, short* l) {
    __builtin_amdgcn_global_load_lds(
        (const __attribute__((address_space(1))) void*)g,
        (__attribute__((address_space(3))) void*)l,
        16, 0, 0);
}

__device__ __forceinline__ float vmax4(floatx4 v) {
    return fmaxf(fmaxf(v[0], v[1]), fmaxf(v[2], v[3]));
}

// ---------------------------------------------------------------------------
// Bulk fp32->bf16 convert: 4 weight matrices (1M elems) + 3 inputs (8.39M).
// ---------------------------------------------------------------------------
__global__ __launch_bounds__(256) void conv_kernel(
    const float* __restrict__ w0, const float* __restrict__ w1,
    const float* __restrict__ w2, const float* __restrict__ w3,
    const float* __restrict__ x0, const float* __restrict__ x1,
    const float* __restrict__ x2,
    short* __restrict__ ow0, short* __restrict__ ow1,
    short* __restrict__ ow2, short* __restrict__ ow3,
    short* __restrict__ ox0, short* __restrict__ ox1,
    short* __restrict__ ox2)
{
    const int z = blockIdx.y;
    const float* src;
    short* dst;
    switch (z) {
        case 0: src = w0; dst = ow0; break;
        case 1: src = w1; dst = ow1; break;
        case 2: src = w2; dst = ow2; break;
        case 3: src = w3; dst = ow3; break;
        case 4: src = x0; dst = ox0; break;
        case 5: src = x1; dst = ox1; break;
        default: src = x2; dst = ox2; break;
    }
    if (z < 4 && blockIdx.x >= 512) return;   // weights: 1M elems only
    size_t i = ((size_t)blockIdx.x * 256 + threadIdx.x) * 8;
    stage8f(dst + i, src + i);
}

// ---------------------------------------------------------------------------
// QKV projection: Y = X @ W^T + b (both operands bf16), m97-structure:
// 128x128 tile, BK=32, LINEAR LDS [128][32], async global_load_lds width=16.
// Output head-split [B,H,S,HD] bf16; Q gets 0.125*log2(e) folded in.
// ---------------------------------------------------------------------------
__global__ __launch_bounds__(256) void proj_kernel(
    const short* __restrict__ xq, const short* __restrict__ xk, const short* __restrict__ xv,
    const short* __restrict__ wqb, const float* __restrict__ bq,
    const short* __restrict__ wkb, const float* __restrict__ bk,
    const short* __restrict__ wvb, const float* __restrict__ bv,
    short* __restrict__ Qh, short* __restrict__ Kh, short* __restrict__ Vh)
{
    const int z = blockIdx.z;
    const short* X  = (z == 0) ? xq  : (z == 1) ? xk  : xv;
    const short* Wb = (z == 0) ? wqb : (z == 1) ? wkb : wvb;
    const float* Bp = (z == 0) ? bq  : (z == 1) ? bk  : bv;
    short* Dst      = (z == 0) ? Qh  : (z == 1) ? Kh  : Vh;
    const float qscale = (z == 0) ? (0.125f * 1.44269504088896f) : 1.0f;

    const int m0 = blockIdx.x * 128;
    const int n0 = blockIdx.y * 128;
    const int tid = threadIdx.x;
    const int w = tid >> 6, lane = tid & 63, lc = lane & 15, lq = lane >> 4;
    const int wm = w >> 1, wn = w & 1;

    // linear row-major [128][32] shorts (8 KB each)
    __shared__ alignas(16) short As[128 * 32];
    __shared__ alignas(16) short Bs[128 * 32];

    // staging map: chunk c (16 rows x 32 cols = 1 KB) staged by wave c%4;
    // lane covers row c*16 + lane/4, cols (lane&3)*8..+7.
    const int rSt = lane >> 2;
    const int cSt = (lane & 3) * 8;

    floatx4 acc[4][4];
#pragma unroll
    for (int i = 0; i < 4; i++)
#pragma unroll
        for (int j = 0; j < 4; j++) acc[i][j] = floatx4{0.f, 0.f, 0.f, 0.f};

    for (int kt = 0; kt < DM / 32; ++kt) {
        __syncthreads();
        {
            const short* gA = X  + (size_t)(m0 + w * 16 + rSt) * DM + kt * 32 + cSt;
            const short* gB = Wb + (size_t)(n0 + w * 16 + rSt) * DM + kt * 32 + cSt;
            gload16(gA,            As + w * 512);
            gload16(gA + 64 * DM,  As + (w + 4) * 512);
            gload16(gB,            Bs + w * 512);
            gload16(gB + 64 * DM,  Bs + (w + 4) * 512);
        }
        __syncthreads();

        bf16x8 aF[4], bF[4];
#pragma unroll
        for (int i = 0; i < 4; i++)
            aF[i] = *(const bf16x8*)(As + (wm * 64 + i * 16 + lc) * 32 + lq * 8);
#pragma unroll
        for (int j = 0; j < 4; j++)
            bF[j] = *(const bf16x8*)(Bs + (wn * 64 + j * 16 + lc) * 32 + lq * 8);
        __builtin_amdgcn_s_setprio(1);
#pragma unroll
        for (int i = 0; i < 4; i++)
#pragma unroll
            for (int j = 0; j < 4; j++)
                acc[i][j] = __builtin_amdgcn_mfma_f32_16x16x32_bf16(aF[i], bF[j], acc[i][j], 0, 0, 0);
        __builtin_amdgcn_s_setprio(0);
    }

#pragma unroll
    for (int j = 0; j < 4; j++) {
        int n = n0 + wn * 64 + j * 16 + lc;
        float bias = Bp[n];
        int h = n >> 6, hd = n & 63;
#pragma unroll
        for (int i = 0; i < 4; i++) {
#pragma unroll
            for (int r = 0; r < 4; r++) {
                int m = m0 + wm * 64 + i * 16 + lq * 4 + r;
                int b = m >> 11, s = m & 2047;
                float val = (acc[i][j][r] + bias) * qscale;
                Dst[(((size_t)(b * NH + h)) * SEQ + s) * HDD + hd] = f2bf(val);
            }
        }
    }
}

// ---------------------------------------------------------------------------
// Flash attention (UNCHANGED from round 7 — passing at 265 us).
// ---------------------------------------------------------------------------
__global__ __launch_bounds__(512) void attn_kernel(
    const short* __restrict__ Qh, const short* __restrict__ Kh,
    const short* __restrict__ Vh, float* __restrict__ ctxout,
    short* __restrict__ ctxb)
{
    // XCD swizzle: 1024 blocks / 8 XCDs -> each XCD owns 8 (b,h) pairs.
    const int linear = blockIdx.y * 16 + blockIdx.x;
    const int swz = (linear & 7) * 128 + (linear >> 3);
    const int qb = swz & 15;
    const int bh = swz >> 4;

    const int tid = threadIdx.x;
    const int w = tid >> 6, lane = tid & 63, lc = lane & 15, lq = lane >> 4;
    const int qbase = qb * 128 + w * 16;

    const short* Qp = Qh + (size_t)bh * SEQ * HDD;
    const short* Kp = Kh + (size_t)bh * SEQ * HDD;
    const short* Vp = Vh + (size_t)bh * SEQ * HDD;

    // V transposed: Vt[buf][half][d*72 + (kv ^ ((d>>3)&7)*8)]  (36,864 B)
    __shared__ alignas(16) short Vt[2][2][64 * 72];
    // Per-wave P scratch: [q=16][one 64-kv tile + 8 pad]  (18,432 B)
    __shared__ alignas(16) short Pl[8][16][72];

    bf16x8 aQ[2];
#pragma unroll
    for (int f = 0; f < 2; ++f)
        aQ[f] = *(const bf16x8*)(Qp + (size_t)(qbase + lc) * HDD + f * 32 + lq * 8);

    float mOld = -1e30f, lSum = 0.f;
    floatx4 accO[4];
#pragma unroll
    for (int dt = 0; dt < 4; dt++) accO[dt] = floatx4{0.f, 0.f, 0.f, 0.f};

    // staging map: 256 threads per half-tile; thread stages 2 kv rows x 8 d
    const int half = tid >> 8;
    const int t8 = tid & 255;
    const int kv2 = (t8 >> 3) * 2;
    const int d0 = (t8 & 7) * 8;
    const int swzb = (t8 & 7) << 3;
    const int kvs_w = kv2 ^ swzb;

    // prologue: stage pair 0 into buf 0
    {
        const short* vp = Vp + (size_t)(half * 64 + kv2) * HDD + d0;
        bf16x8 v0 = *(const bf16x8*)vp;
        bf16x8 v1 = *(const bf16x8*)(vp + HDD);
        short* dstb = &Vt[0][half][0];
#pragma unroll
        for (int i = 0; i < 8; i++) {
            u32 pk = ((u32)(unsigned short)v0[i]) | (((u32)(unsigned short)v1[i]) << 16);
            *(u32*)(dstb + (d0 + i) * 72 + kvs_w) = pk;
        }
    }
    __syncthreads();

    short* plw = &Pl[w][0][0] + lc * 72;   // this lane's P row (q = lc)

    const int NP = SEQ / 128;  // 16 iterations
    for (int kp = 0; kp < NP; ++kp) {
        const int cur = kp & 1;
        const int kv0 = kp * 128;
        const bool have = (kp + 1 < NP);

        // early-issue next pair's V loads (hide under QK+softmax+PV)
        bf16x8 nv0{}, nv1{};
        if (have) {
            const short* nvp = Vp + (size_t)(kv0 + 128 + half * 64 + kv2) * HDD + d0;
            nv0 = *(const bf16x8*)nvp;
            nv1 = *(const bf16x8*)(nvp + HDD);
        }

        // QK^T for both tiles (scores in log2-units; scale folded into Q)
        floatx4 sc0[4], sc1[4];
        __builtin_amdgcn_s_setprio(1);
#pragma unroll
        for (int nt = 0; nt < 4; nt++) {
            floatx4 sv = floatx4{0.f, 0.f, 0.f, 0.f};
#pragma unroll
            for (int f = 0; f < 2; f++) {
                bf16x8 bK = *(const bf16x8*)(Kp + (size_t)(kv0 + nt * 16 + lc) * HDD + f * 32 + lq * 8);
                sv = __builtin_amdgcn_mfma_f32_16x16x32_bf16(bK, aQ[f], sv, 0, 0, 0);
            }
            sc0[nt] = sv;
        }
#pragma unroll
        for (int nt = 0; nt < 4; nt++) {
            floatx4 sv = floatx4{0.f, 0.f, 0.f, 0.f};
#pragma unroll
            for (int f = 0; f < 2; f++) {
                bf16x8 bK = *(const bf16x8*)(Kp + (size_t)(kv0 + 64 + nt * 16 + lc) * HDD + f * 32 + lq * 8);
                sv = __builtin_amdgcn_mfma_f32_16x16x32_bf16(bK, aQ[f], sv, 0, 0, 0);
            }
            sc1[nt] = sv;
        }
        __builtin_amdgcn_s_setprio(0);

        // max over 128 kv: in-lane tree + 2 shfl
        float ma = fmaxf(fmaxf(vmax4(sc0[0]), vmax4(sc0[1])),
                         fmaxf(vmax4(sc0[2]), vmax4(sc0[3])));
        float mb = fmaxf(fmaxf(vmax4(sc1[0]), vmax4(sc1[1])),
                         fmaxf(vmax4(sc1[2]), vmax4(sc1[3])));
        float mx = fmaxf(ma, mb);
        mx = fmaxf(mx, __shfl_xor(mx, 16, 64));
        mx = fmaxf(mx, __shfl_xor(mx, 32, 64));
        if (!__all(mx - mOld <= 8.0f)) {
            const float mNew = fmaxf(mOld, mx);
            const float alpha = __builtin_amdgcn_exp2f(mOld - mNew);
            lSum *= alpha;
#pragma unroll
            for (int dt = 0; dt < 4; dt++)
#pragma unroll
                for (int r = 0; r < 4; r++) accO[dt][r] *= alpha;
            mOld = mNew;
        }

        // exp2 + tree-sum
        float part[8];
#pragma unroll
        for (int nt = 0; nt < 4; nt++) {
            floatx4 p0 = sc0[nt], p1 = sc1[nt];
#pragma unroll
            for (int r = 0; r < 4; r++) {
                p0[r] = __builtin_amdgcn_exp2f(p0[r] - mOld);
                p1[r] = __builtin_amdgcn_exp2f(p1[r] - mOld);
            }
            sc0[nt] = p0; sc1[nt] = p1;
            part[nt]     = (p0[0] + p0[1]) + (p0[2] + p0[3]);
            part[4 + nt] = (p1[0] + p1[1]) + (p1[2] + p1[3]);
        }
        float rsum = ((part[0] + part[1]) + (part[2] + part[3])) +
                     ((part[4] + part[5]) + (part[6] + part[7]));
        rsum += __shfl_xor(rsum, 16, 64);
        rsum += __shfl_xor(rsum, 32, 64);
        lSum += rsum;

        // PV per 64-kv tile: write P_t to the wave-local row (offsets
        // nt*16+lq*4 <= 60 < 72), read back as B-fragments, 8 MFMA.
#pragma unroll
        for (int t = 0; t < 2; t++) {
            floatx4* sc = (t == 0) ? sc0 : sc1;
#pragma unroll
            for (int nt = 0; nt < 4; nt++) {
                uint2 pr;
                pr.x = cvt_pk_bf16(sc[nt][0], sc[nt][1]);
                pr.y = cvt_pk_bf16(sc[nt][2], sc[nt][3]);
                *(uint2*)(plw + nt * 16 + lq * 4) = pr;
            }
            const short* vtb = &Vt[cur][t][0];
#pragma unroll
            for (int f = 0; f < 2; f++) {
                bf16x8 aP = *(const bf16x8*)(plw + f * 32 + lq * 8);
                __builtin_amdgcn_s_setprio(1);
#pragma unroll
                for (int dt = 0; dt < 4; dt++) {
                    const int d = dt * 16 + lc;
                    const int kvs = (f * 32 + lq * 8) ^ (((d >> 3) & 7) << 3);
                    bf16x8 bV = *(const bf16x8*)(vtb + d * 72 + kvs);
                    accO[dt] = __builtin_amdgcn_mfma_f32_16x16x32_bf16(bV, aP, accO[dt], 0, 0, 0);
                }
                __builtin_amdgcn_s_setprio(0);
            }
        }

        // write next pair's V into the other buffer
        if (have) {
            short* dstb = &Vt[cur ^ 1][half][0];
#pragma unroll
            for (int i = 0; i < 8; i++) {
                u32 pk = ((u32)(unsigned short)nv0[i]) | (((u32)(unsigned short)nv1[i]) << 16);
                *(u32*)(dstb + (d0 + i) * 72 + kvs_w) = pk;
            }
        }
        __syncthreads();
    }

    // epilogue: ctx[b,h,q,d] = O^T[d][q] / l (fp32 to d_out, bf16 to ws)
    const float inv = 1.0f / lSum;
    const size_t rowoff = ((size_t)bh * SEQ + qbase + lc) * HDD;
    float* orow = ctxout + rowoff;
    short* brow = ctxb + rowoff;
#pragma unroll
    for (int dt = 0; dt < 4; dt++) {
        float4 st;
        st.x = accO[dt][0] * inv;
        st.y = accO[dt][1] * inv;
        st.z = accO[dt][2] * inv;
        st.w = accO[dt][3] * inv;
        *(float4*)(orow + dt * 16 + lq * 4) = st;
        uint2 bb;
        bb.x = cvt_pk_bf16(st.x, st.y);
        bb.y = cvt_pk_bf16(st.z, st.w);
        *(uint2*)(brow + dt * 16 + lq * 4) = bb;
    }
}

// ---------------------------------------------------------------------------
// Output projection: out = merged(ctx) @ Wo^T + bo, m97-structure with
// async global_load_lds; A gathered per-lane from head-split ctxb.
// ---------------------------------------------------------------------------
__global__ __launch_bounds__(256) void outproj_kernel(
    const short* __restrict__ ctxb, const short* __restrict__ wob,
    const float* __restrict__ bo, float* __restrict__ out)
{
    const int m0 = blockIdx.x * 128;
    const int n0 = blockIdx.y * 128;
    const int tid = threadIdx.x;
    const int w = tid >> 6, lane = tid & 63, lc = lane & 15, lq = lane >> 4;
    const int wm = w >> 1, wn = w & 1;

    __shared__ alignas(16) short As[128 * 32];
    __shared__ alignas(16) short Bs[128 * 32];

    const int rSt = lane >> 2;
    const int cSt = (lane & 3) * 8;

    floatx4 acc[4][4];
#pragma unroll
    for (int i = 0; i < 4; i++)
#pragma unroll
        for (int j = 0; j < 4; j++) acc[i][j] = floatx4{0.f, 0.f, 0.f, 0.f};

    for (int kt = 0; kt < DM / 32; ++kt) {
        const int h = kt >> 1;               // kcol = kt*32 + cSt -> h const/kt
        const int hd0 = (kt & 1) * 32 + cSt;
        __syncthreads();
        {
            // A rows m = m0 + chunk*16 + rSt (chunks w, w+4), gathered:
            int mA0 = m0 + w * 16 + rSt;
            int mA1 = mA0 + 64;
            int b0 = mA0 >> 11, s0 = mA0 & 2047;
            int b1 = mA1 >> 11, s1 = mA1 & 2047;
            const short* gA0 = ctxb + (((size_t)(b0 * NH + h)) * SEQ + s0) * HDD + hd0;
            const short* gA1 = ctxb + (((size_t)(b1 * NH + h)) * SEQ + s1) * HDD + hd0;
            const short* gB  = wob + (size_t)(n0 + w * 16 + rSt) * DM + kt * 32 + cSt;
            gload16(gA0,          As + w * 512);
            gload16(gA1,          As + (w + 4) * 512);
            gload16(gB,           Bs + w * 512);
            gload16(gB + 64 * DM, Bs + (w + 4) * 512);
        }
        __syncthreads();

        bf16x8 aF[4], bF[4];
#pragma unroll
        for (int i = 0; i < 4; i++)
            aF[i] = *(const bf16x8*)(As + (wm * 64 + i * 16 + lc) * 32 + lq * 8);
#pragma unroll
        for (int j = 0; j < 4; j++)
            bF[j] = *(const bf16x8*)(Bs + (wn * 64 + j * 16 + lc) * 32 + lq * 8);
        __builtin_amdgcn_s_setprio(1);
#pragma unroll
        for (int i = 0; i < 4; i++)
#pragma unroll
            for (int j = 0; j < 4; j++)
                acc[i][j] = __builtin_amdgcn_mfma_f32_16x16x32_bf16(aF[i], bF[j], acc[i][j], 0, 0, 0);
        __builtin_amdgcn_s_setprio(0);
    }

#pragma unroll
    for (int j = 0; j < 4; j++) {
        int n = n0 + wn * 64 + j * 16 + lc;
        float bias = bo[n];
#pragma unroll
        for (int i = 0; i < 4; i++) {
#pragma unroll
            for (int r = 0; r < 4; r++) {
                int m = m0 + wm * 64 + i * 16 + lq * 4 + r;
                out[(size_t)m * DM + n] = acc[i][j][r] + bias;
            }
        }
    }
}

extern "C" void kernel_launch(void* const* d_in, const int* in_sizes, int n_in,
                              void* d_out, int out_size, void* d_ws, size_t ws_size,
                              hipStream_t stream) {
    const float* q  = (const float*)d_in[0];
    const float* k  = (const float*)d_in[1];
    const float* v  = (const float*)d_in[2];
    const float* wq = (const float*)d_in[3];
    const float* bq = (const float*)d_in[4];
    const float* wk = (const float*)d_in[5];
    const float* bk = (const float*)d_in[6];
    const float* wv = (const float*)d_in[7];
    const float* bv = (const float*)d_in[8];
    const float* wo = (const float*)d_in[9];
    const float* bo = (const float*)d_in[10];

    float* out0 = (float*)d_out;                          // [B,S,D] fp32
    float* ctx  = out0 + (size_t)BB * SEQ * DM;           // [B,H,S,HD] fp32

    const size_t NELEM = (size_t)BB * NH * SEQ * HDD;     // 8.39M
    short* Qh   = (short*)d_ws;
    short* Kh   = Qh + NELEM;
    short* Vh   = Kh + NELEM;
    short* ctxb = Vh + NELEM;           // written by attn; until then holds Xv
    short* Wqb  = ctxb + NELEM;
    short* Wkb  = Wqb + (size_t)DM * DM;
    short* Wvb  = Wkb + (size_t)DM * DM;
    short* Wob  = Wvb + (size_t)DM * DM;
    // bf16 X: Xq/Xk borrow d_out's out0 region (written only by outproj at
    // the end); Xv aliases ctxb (written only by attn, after proj reads Xv).
    short* Xq = (short*)out0;
    short* Xk = Xq + NELEM;
    short* Xv = ctxb;

    conv_kernel<<<dim3(4096, 7), 256, 0, stream>>>(
        wq, wk, wv, wo, q, k, v, Wqb, Wkb, Wvb, Wob, Xq, Xk, Xv);
    proj_kernel<<<dim3(64, 8, 3), 256, 0, stream>>>(
        Xq, Xk, Xv, Wqb, bq, Wkb, bk, Wvb, bv, Qh, Kh, Vh);
    attn_kernel<<<dim3(16, 64), 512, 0, stream>>>(Qh, Kh, Vh, ctx, ctxb);
    outproj_kernel<<<dim3(64, 8), 256, 0, stream>>>(ctxb, Wob, bo, out0);
}